// Round 2
// baseline (204.092 us; speedup 1.0000x reference)
//
#include <hip/hip_runtime.h>

// VQ-VAE loss: B=2, Q=64, K=512, N=1024, C=256, STRIDE=64, Nw=N*64-1=65535
//
// reference = mean_{b,t} [ logsoftmax(quant_pred)[b, tgt[b,t], t]
//                          + 1.25 * min_k sum_q (ze[b,q,t/64] - emb[k,t/64])^2 ]
//
// min_k sum_q (v_q - e)^2 = S2 - 2 e S1 + Q e^2  with S1=sum_q v, S2=sum_q v^2.
//
// Single fused kernel. Class dim is split across wave pairs (2 halves x 128
// classes) to double occupancy to 4 waves/SIMD, and the class stream uses a
// ping-pong 8-deep double buffer (16 outstanding dwords/wave, no vmcnt(0)
// drain per group) so HBM latency is covered: ~16KB in flight per SIMD vs
// ~2.3KB required at 6.3 TB/s.
//
// Block = 256 threads = 4 waves over 128 consecutive wav positions:
//   wave 0: t..t+63,     classes   0..127   (+ VQ min + target gather)
//   wave 1: t+64..t+127, classes   0..127   (+ VQ min + target gather)
//   wave 2: t..t+63,     classes 128..255
//   wave 3: t+64..t+127, classes 128..255
// Halves merge their online-(m,s) via one LDS exchange.

#define QQ   64
#define NN   1024
#define KK   512
#define CLS  256
#define NW   65535

__global__ __launch_bounds__(256) void vq_fused_kernel(
        const float* __restrict__ qp,
        const float* __restrict__ ze,
        const float* __restrict__ emb,
        const int*   __restrict__ tgt,
        float* __restrict__ out)
{
    const int lane = threadIdx.x & 63;
    const int wv   = threadIdx.x >> 6;        // 0..3
    const int half = wv >> 1;                 // class half (wave-uniform)
    const int posw = wv & 1;                  // which 64-position window
    const int g    = blockIdx.x * 128 + posw * 64 + lane;
    const int b    = g >> 16;                 // block-uniform (128 | 65536)
    const int t    = g & 0xFFFF;
    const bool valid = (t < NW);
    const int tc   = valid ? t : (NW - 1);    // clamp; contribution zeroed below
    const int n    = tc >> 6;                 // wave-uniform

    const float* p = qp + (size_t)b * CLS * NW + tc;
    const int cb = half * 128;                // this thread's class base

    // ---- issue first two 8-deep groups (ping-pong buffers) ---------------
    float bufA[8], bufB[8];
    #pragma unroll
    for (int u = 0; u < 8; ++u) bufA[u] = p[(size_t)(cb + u) * NW];
    #pragma unroll
    for (int u = 0; u < 8; ++u) bufB[u] = p[(size_t)(cb + 8 + u) * NW];

    // ---- half 0 also owns target gather + VQ min (overlaps the loads) ----
    float tv = 0.0f, l2 = 0.0f;
    if (half == 0) {
        int tg = tgt[(size_t)b * NW + tc];
        tv = p[(size_t)tg * NW];              // one gather vs 256 compares

        float v  = ze[(size_t)(b * QQ + lane) * NN + n];   // lane = q
        float s1 = v, s2 = v * v;
        #pragma unroll
        for (int msk = 32; msk >= 1; msk >>= 1) {
            s1 += __shfl_xor(s1, msk, 64);
            s2 += __shfl_xor(s2, msk, 64);
        }
        float best = 3.4e38f;
        float n2s1 = -2.0f * s1;
        #pragma unroll
        for (int j = 0; j < KK / 64; ++j) {   // lane strided over k
            float e = emb[(size_t)(lane + 64 * j) * NN + n];
            best = fminf(best, fmaf(e, fmaf((float)QQ, e, n2s1), s2));
        }
        #pragma unroll
        for (int msk = 32; msk >= 1; msk >>= 1)
            best = fminf(best, __shfl_xor(best, msk, 64));
        l2 = 1.25f * best;                    // l2 + 0.25*commit
    }

    // ---- online logsumexp over this half's 128 classes -------------------
    float m = -3.4e38f, s = 0.0f;
    auto merge8 = [&](const float* x) {
        float m01 = fmaxf(x[0], x[1]), m23 = fmaxf(x[2], x[3]);
        float m45 = fmaxf(x[4], x[5]), m67 = fmaxf(x[6], x[7]);
        float m8  = fmaxf(fmaxf(m01, m23), fmaxf(m45, m67));
        float s8  = __expf(x[0] - m8) + __expf(x[1] - m8)
                  + __expf(x[2] - m8) + __expf(x[3] - m8)
                  + __expf(x[4] - m8) + __expf(x[5] - m8)
                  + __expf(x[6] - m8) + __expf(x[7] - m8);
        float nm  = fmaxf(m, m8);
        s = s * __expf(m - nm) + s8 * __expf(m8 - nm);
        m = nm;
    };

    // 16 groups of 8; g0 in A, g1 in B; steady state keeps 16 loads in flight
    #pragma unroll
    for (int k = 0; k < 14; k += 2) {
        merge8(bufA);                          // waits only on A's 8 loads
        #pragma unroll
        for (int u = 0; u < 8; ++u) bufA[u] = p[(size_t)(cb + (k + 2) * 8 + u) * NW];
        merge8(bufB);
        #pragma unroll
        for (int u = 0; u < 8; ++u) bufB[u] = p[(size_t)(cb + (k + 3) * 8 + u) * NW];
    }
    merge8(bufA);                              // group 14
    merge8(bufB);                              // group 15

    // ---- merge the two class halves via LDS ------------------------------
    __shared__ float msh[128][2];
    __shared__ float part[2];
    const int pos = posw * 64 + lane;
    if (half == 1) { msh[pos][0] = m; msh[pos][1] = s; }
    __syncthreads();

    if (half == 0) {
        float m1  = msh[pos][0], s1v = msh[pos][1];
        float nm  = fmaxf(m, m1);
        float ss  = s * __expf(m - nm) + s1v * __expf(m1 - nm);
        float lse = nm + __logf(ss);
        float contrib = valid ? (tv - lse + l2) : 0.0f;
        #pragma unroll
        for (int msk = 32; msk >= 1; msk >>= 1)
            contrib += __shfl_xor(contrib, msk, 64);
        if (lane == 0) part[wv] = contrib;     // wv = 0 or 1
    }
    __syncthreads();
    if (threadIdx.x == 0)
        atomicAdd(out, (part[0] + part[1]) * (1.0f / 131070.0f));  // mean B*Nw
}

extern "C" void kernel_launch(void* const* d_in, const int* in_sizes, int n_in,
                              void* d_out, int out_size, void* d_ws, size_t ws_size,
                              hipStream_t stream) {
    const float* quant_pred = (const float*)d_in[0];   // (B, 256, 65535) fp32
    const float* ze         = (const float*)d_in[1];   // (B, 64, 1024)   fp32
    const float* emb        = (const float*)d_in[2];   // (512, 1024)     fp32
    const int*   target     = (const int*)  d_in[3];   // (B, 1, 65535)   int32
    float* out = (float*)d_out;                        // scalar fp32
    (void)d_ws; (void)ws_size; (void)in_sizes; (void)n_in; (void)out_size;

    hipMemsetAsync(out, 0, sizeof(float), stream);
    vq_fused_kernel<<<1024, 256, 0, stream>>>(quant_pred, ze, emb, target, out);
}